// Round 13
// baseline (251.817 us; speedup 1.0000x reference)
//
#include <hip/hip_runtime.h>
#include <cstdint>
#include <cstddef>

// R12 = R9 dataflow pipelined (R10's deferral) x R11's Wc-in-regs:
//   h2_{i+1} = u_i*hg_i + (1-u_i)*h1n_{i-1}  -> y/act of step i-1 computed
//   inside step i's phase 1; W2+blend in phase 2. 2 barriers/step (R9: 3).
// R10 failed with 12 b128 in phase 1 (Wc from LDS); here phase 1 has 8
// (4 sH2 + 4 sH-prev), Wc/W2 in regs (R11 layout, ~80 f16x2 persistent).
// Arithmetic identical to R9/R10 -> absmax must stay exactly 9.765625e-4.
// Kept: gi fused prologue, rank pairing, 1 row/WG, 512thr, DPP qred4,
// lgkmcnt-only barriers. Fallback: R5 exact kernel.
// Predicted: ~195-215us (>=229 falsifies; revert to R9). VALU ~60-65%.

typedef _Float16 f16;
typedef _Float16 f16x2 __attribute__((ext_vector_type(2)));

#define NSTEP 127
#define NSUB 10
#define B_LEN 512
#define S_LEN 128
#define H_LEN 128

__device__ __forceinline__ float dot2acc(f16x2 a, f16x2 b, float c) {
  return __builtin_amdgcn_fdot2(a, b, c, false);
}
__device__ __forceinline__ f16x2 bchalf(unsigned int u) {
  return __builtin_bit_cast(f16x2, u);
}

__device__ __forceinline__ float qred4(float v) {
  int a = __builtin_bit_cast(int, v);
  int b = __builtin_amdgcn_update_dpp(0, a, 0xB1, 0xF, 0xF, true);  // xor 1
  float v1 = v + __builtin_bit_cast(float, b);
  int c = __builtin_bit_cast(int, v1);
  int d = __builtin_amdgcn_update_dpp(0, c, 0x4E, 0xF, 0xF, true);  // xor 2
  return v1 + __builtin_bit_cast(float, d);
}

__device__ __forceinline__ void wg_barrier() {
  asm volatile("s_waitcnt lgkmcnt(0)\n\ts_barrier" ::: "memory");
}

#define DOT4R(acc, wr, base, dv)                          \
  do {                                                    \
    acc = dot2acc((wr)[(base) + 0], bchalf((dv).x), acc); \
    acc = dot2acc((wr)[(base) + 1], bchalf((dv).y), acc); \
    acc = dot2acc((wr)[(base) + 2], bchalf((dv).z), acc); \
    acc = dot2acc((wr)[(base) + 3], bchalf((dv).w), acc); \
  } while (0)

// JAX threefry2x32 (20 rounds) -- bit-exact (verified: absmax <=2e-3).
__device__ __forceinline__ void tf2x32(unsigned int k0, unsigned int k1,
                                       unsigned int& x0, unsigned int& x1) {
  unsigned int ks[3] = {k0, k1, k0 ^ k1 ^ 0x1BD11BDAu};
  x0 += ks[0];
  x1 += ks[1];
  const int R[2][4] = {{13, 15, 26, 6}, {17, 29, 16, 24}};
#pragma unroll
  for (int g = 0; g < 5; ++g) {
#pragma unroll
    for (int j = 0; j < 4; ++j) {
      const int r = R[g & 1][j];
      x0 += x1;
      x1 = (x1 << r) | (x1 >> (32 - r));
      x1 ^= x0;
    }
    x0 += ks[(g + 1) % 3];
    x1 += ks[(g + 2) % 3] + (unsigned int)(g + 1);
  }
}

__device__ __forceinline__ float erfinv_f32(float x) {
  float w = -log1pf(-x * x);
  float p;
  if (w < 5.0f) {
    w = w - 2.5f;
    p = 2.81022636e-08f;
    p = fmaf(p, w, 3.43273939e-07f);
    p = fmaf(p, w, -3.5233877e-06f);
    p = fmaf(p, w, -4.39150654e-06f);
    p = fmaf(p, w, 0.00021858087f);
    p = fmaf(p, w, -0.00125372503f);
    p = fmaf(p, w, -0.00417768164f);
    p = fmaf(p, w, 0.246640727f);
    p = fmaf(p, w, 1.50140941f);
  } else {
    w = sqrtf(w) - 3.0f;
    p = -0.000200214257f;
    p = fmaf(p, w, 0.000100950558f);
    p = fmaf(p, w, 0.00134934322f);
    p = fmaf(p, w, -0.00367342844f);
    p = fmaf(p, w, 0.00573950773f);
    p = fmaf(p, w, -0.0076224613f);
    p = fmaf(p, w, 0.00943887047f);
    p = fmaf(p, w, 1.00167406f);
    p = fmaf(p, w, 2.83297682f);
  }
  return p * x;
}

__device__ __forceinline__ float frcp(float x) {
  return __builtin_amdgcn_rcpf(x);
}
__device__ __forceinline__ float fsig(float x) {
  return frcp(1.0f + __expf(-x));
}
__device__ __forceinline__ float ftanh_fast(float x) {
  return 1.0f - 2.0f * frcp(__expf(2.0f * x) + 1.0f);
}
__device__ __forceinline__ float fsoftplus(float x) {
  return fmaxf(x, 0.0f) + __logf(1.0f + __expf(-fabsf(x)));
}

// ---- td precompute
__global__ __launch_bounds__(256) void td_kernel(
    const float* __restrict__ times, const int* __restrict__ non_zero,
    float* __restrict__ wsTd) {
  __shared__ float sA[256], sB[256];
  __shared__ int sC[256];
  const int i = blockIdx.x;
  const int t = threadIdx.x;
  float s1 = 0.f, s2 = 0.f;
  int c = 0;
  for (int b = t; b < B_LEN; b += 256) {
    const int nz = non_zero[b];
    const float t1 = times[b * S_LEN + i + 1];
    const bool v = (i < nz - 1) && (t1 != 0.0f);
    if (v) {
      c += 1;
      s1 += times[b * S_LEN + i];
      s2 += t1;
    }
  }
  sA[t] = s1;
  sB[t] = s2;
  sC[t] = c;
  __syncthreads();
  for (int o = 128; o > 0; o >>= 1) {
    if (t < o) {
      sA[t] += sA[t + o];
      sB[t] += sB[t + o];
      sC[t] += sC[t + o];
    }
    __syncthreads();
  }
  if (t == 0) {
    const float cnt = (float)((sC[0] < 1) ? 1 : sC[0]);
    const float ts = sA[0] / cnt * 0.02f;
    const float te = sB[0] / cnt * 0.02f;
    wsTd[i] = (te == ts) ? 1.0f : (te - ts);
  }
}

// ---- A/B/c/e precompute (only needed by the R5 fallback kernel)
__global__ __launch_bounds__(128) void ab_kernel(
    const float* __restrict__ dW1, const float* __restrict__ gW1,
    const float* __restrict__ dW2, const float* __restrict__ gW2,
    const float* __restrict__ db2, const float* __restrict__ gb2,
    float* __restrict__ wsC, float* __restrict__ wsE, f16* __restrict__ wsA,
    f16* __restrict__ wsB) {
  __shared__ float sWc[128];
  const int o = blockIdx.x;
  const int j = threadIdx.x;
  sWc[j] = (o < 64) ? dW1[o * 128 + j] : gW1[(o - 64) * 128 + j];
  __syncthreads();
  float acc = 0.f;
  if (j < 64) {
    for (int m = 0; m < 128; ++m) acc += sWc[m] * dW2[m * 64 + j];
    wsA[o * 64 + j] = (f16)acc;
  } else {
    const int jj = j - 64;
    for (int m = 0; m < 128; ++m) acc += sWc[m] * gW2[m * 64 + jj];
    wsB[o * 64 + jj] = (f16)acc;
  }
  if (j == 0) {
    float cc = 0.f;
    for (int m = 0; m < 128; ++m) cc += sWc[m] * db2[m];
    wsC[o] = cc;
  }
  if (j == 1) {
    float ee = 0.f;
    for (int m = 0; m < 128; ++m) ee += sWc[m] * gb2[m];
    wsE[o] = ee;
  }
}

// ---- rank permutation: longest-with-shortest pairing.
__global__ __launch_bounds__(512) void rank_kernel(
    const int* __restrict__ non_zero, int* __restrict__ wsPerm) {
  __shared__ int sL[512];
  const int t = threadIdx.x;
  sL[t] = non_zero[t];
  __syncthreads();
  const int Li = sL[t];
  int r = 0;
  for (int j = 0; j < 512; ++j) {
    const int Lj = sL[j];
    r += (Lj > Li) || (Lj == Li && j < t);
  }
  const int g = (r < 256) ? r : (767 - r);
  wsPerm[g] = t;
}

// ---- main scan: 1 row/WG, gi prologue fused, pipelined 2 barriers/step,
//      Wc+W2 in registers (phase 1 = 8 x b128 only).
__global__ __launch_bounds__(512, 4) void sde_scan6(
    const int* __restrict__ non_zero, const float* __restrict__ inputs,
    const float* __restrict__ Wih, const float* __restrict__ bih,
    const float* __restrict__ Whh, const float* __restrict__ bhh,
    const float* __restrict__ dW1, const float* __restrict__ db1,
    const float* __restrict__ dW2, const float* __restrict__ db2,
    const float* __restrict__ gW1, const float* __restrict__ gb1,
    const float* __restrict__ gW2, const float* __restrict__ gb2,
    const float* __restrict__ wsTd, f16* __restrict__ wsGi,
    const int* __restrict__ wsPerm, float* __restrict__ out) {
  __shared__ __align__(16) f16 sXall[NSTEP * 128];  // 32.5KB all x for row
  __shared__ f16 sZ[NSTEP * NSUB];
  __shared__ float sTdv[NSTEP], sSq[NSTEP], sU[NSTEP], sZsum[NSTEP];
  __shared__ __align__(16) f16 sH2[H_LEN], sSa[H_LEN];
  __shared__ __align__(16) f16 sH[2][H_LEN];  // dbuf: hg_i / hg_{i-1}

  const int t = threadIdx.x;
  const int kq = t & 3;
  const int oq = t >> 2;
  const int kb32 = kq * 32;
  const int kb16 = kq * 16;
  const int b = wsPerm[blockIdx.x];  // permuted row
  const int L = non_zero[b] - 1;

  // noise (bit-stream identical to R0-R11; only per-step sums feed the model)
  for (int idx = t; idx < NSTEP * NSUB; idx += 512) {
    unsigned int f0 = 0u, f1 = (unsigned int)idx;
    tf2x32(0u, 42u, f0, f1);
    unsigned int y0 = 0u, y1 = (unsigned int)b;
    tf2x32(f0, f1, y0, y1);
    const unsigned int bits = y1;
    const float fl = __uint_as_float((bits >> 9) | 0x3F800000u) - 1.0f;
    const float lo = __uint_as_float(0xBF7FFFFFu);
    float u = fl * (1.0f - lo) + lo;
    u = fmaxf(lo, u);
    sZ[idx] = (f16)(1.41421356237f * erfinv_f32(u));
  }
  if (t < NSTEP) {
    const float td = wsTd[t];
    sTdv[t] = td;
    sSq[t] = sqrtf(td * 0.1f);
    sU[t] = (t == 0) ? 1.0f : __expf(-wsTd[t - 1]);
  }
  // bulk x staging: all 127 steps of this row, f32 -> f16
  for (int idx = t; idx < NSTEP * 128; idx += 512) {
    const int i = idx >> 7, h = idx & 127;
    sXall[idx] = (f16)inputs[((size_t)i * B_LEN + b) * H_LEN + h];
  }
  if (kq == 0) sH2[oq] = (f16)0.f;
  __syncthreads();
  if (t < NSTEP) {
    float s = 0.f;
#pragma unroll
    for (int k = 0; k < NSUB; ++k) s += (float)sZ[t * NSUB + k];
    sZsum[t] = s;
  }

  // ---- gi prologue: rW holds Wih slices now, Whh later (same registers)
  f16x2 rW[3][16];
#pragma unroll
  for (int g = 0; g < 3; ++g) {
    const float* pi = Wih + (size_t)(oq + 128 * g) * 128 + kb32;
#pragma unroll
    for (int c = 0; c < 16; ++c) {
      f16x2 a;
      a[0] = (f16)pi[2 * c];
      a[1] = (f16)pi[2 * c + 1];
      rW[g][c] = a;
    }
  }
  {
    const float bi0 = bih[oq];
    const float bi1 = bih[oq + 128];
    const float bi2 = bih[oq + 256];
    uint2* giOut = (uint2*)wsGi + (size_t)b * NSTEP * 128 + oq;
    for (int i = 0; i < NSTEP; ++i) {
      float a0 = 0.f, a1 = 0.f, a2 = 0.f;
#pragma unroll
      for (int c = 0; c < 4; ++c) {
        const uint4 xv = *(const uint4*)&sXall[i * 128 + kb32 + c * 8];
        DOT4R(a0, rW[0], c * 4, xv);
        DOT4R(a1, rW[1], c * 4, xv);
        DOT4R(a2, rW[2], c * 4, xv);
      }
      const float g0 = qred4(a0) + bi0;
      const float g1 = qred4(a1) + bi1;
      const float g2 = qred4(a2) + bi2;
      if (kq == 0) {
        union {
          f16 h[4];
          uint2 u2;
        } pk;
        pk.h[0] = (f16)g0;
        pk.h[1] = (f16)g1;
        pk.h[2] = (f16)g2;
        pk.h[3] = (f16)0.f;
        giOut[(size_t)i * 128] = pk.u2;
      }
    }
  }
  __syncthreads();  // full drain: gi stores visible to all lanes

  // ---- reload rW with Whh; load Wc (y-init) + W2 slices into registers
#pragma unroll
  for (int g = 0; g < 3; ++g) {
    const float* ph = Whh + (size_t)(oq + 128 * g) * 128 + kb32;
#pragma unroll
    for (int c = 0; c < 16; ++c) {
      f16x2 bb;
      bb[0] = (f16)ph[2 * c];
      bb[1] = (f16)ph[2 * c + 1];
      rW[g][c] = bb;
    }
  }
  f16x2 rW1[16];  // Wc[oq][kb32..+32) -- loop-invariant, in regs
  {
    const float* p1 = (oq < 64) ? (dW1 + (size_t)oq * 128 + kb32)
                                : (gW1 + (size_t)(oq - 64) * 128 + kb32);
#pragma unroll
    for (int c = 0; c < 16; ++c) {
      f16x2 a;
      a[0] = (f16)p1[2 * c];
      a[1] = (f16)p1[2 * c + 1];
      rW1[c] = a;
    }
  }
  f16x2 rW2d[8], rW2g[8];
  {
    const float* pd = dW2 + (size_t)oq * 64 + kb16;
    const float* pg = gW2 + (size_t)oq * 64 + kb16;
#pragma unroll
    for (int c = 0; c < 8; ++c) {
      f16x2 a;
      a[0] = (f16)pd[2 * c];
      a[1] = (f16)pd[2 * c + 1];
      rW2d[c] = a;
      f16x2 bb;
      bb[0] = (f16)pg[2 * c];
      bb[1] = (f16)pg[2 * c + 1];
      rW2g[c] = bb;
    }
  }
  const float bhh0 = bhh[oq];
  const float bhh1 = bhh[oq + 128];
  const float bhh2 = bhh[oq + 256];
  const float bias1 = (oq < 64) ? db1[oq] : gb1[oq - 64];
  const float b2d = db2[oq], b2g = gb2[oq];

  float h2e = 0.f, hgPrev = 0.f;
  const uint2* gi2 = (const uint2*)wsGi + (size_t)b * NSTEP * 128 + oq;
  uint2 giReg = gi2[0];

  for (int i = 0; i < L; ++i) {
    // ---- phase 1: GRU(Whh x h2_i)  ||  y_{i-1} = Wc x hg_{i-1} (regs)
    float ah0a = 0.f, ah1a = 0.f, ah2a = 0.f;
    float ah0b = 0.f, ah1b = 0.f, ah2b = 0.f;
    {
      const uint4 hv0 = *(const uint4*)&sH2[kb32];
      const uint4 hv1 = *(const uint4*)&sH2[kb32 + 8];
      const uint4 hv2 = *(const uint4*)&sH2[kb32 + 16];
      const uint4 hv3 = *(const uint4*)&sH2[kb32 + 24];
      DOT4R(ah0a, rW[0], 0, hv0);
      DOT4R(ah0a, rW[0], 4, hv1);
      DOT4R(ah0b, rW[0], 8, hv2);
      DOT4R(ah0b, rW[0], 12, hv3);
      DOT4R(ah1a, rW[1], 0, hv0);
      DOT4R(ah1a, rW[1], 4, hv1);
      DOT4R(ah1b, rW[1], 8, hv2);
      DOT4R(ah1b, rW[1], 12, hv3);
      DOT4R(ah2a, rW[2], 0, hv0);
      DOT4R(ah2a, rW[2], 4, hv1);
      DOT4R(ah2b, rW[2], 8, hv2);
      DOT4R(ah2b, rW[2], 12, hv3);
    }
    float ya = 0.f, yb = 0.f;
    if (i > 0) {
      const f16* sHp = sH[(i + 1) & 1];  // hg_{i-1}
      const uint4 hv0 = *(const uint4*)&sHp[kb32];
      const uint4 hv1 = *(const uint4*)&sHp[kb32 + 8];
      const uint4 hv2 = *(const uint4*)&sHp[kb32 + 16];
      const uint4 hv3 = *(const uint4*)&sHp[kb32 + 24];
      DOT4R(ya, rW1, 0, hv0);
      DOT4R(ya, rW1, 4, hv1);
      DOT4R(yb, rW1, 8, hv2);
      DOT4R(yb, rW1, 12, hv3);
    }
    const f16x2 g01 = bchalf(giReg.x);
    const f16x2 g2p = bchalf(giReg.y);
    const float gi0 = (float)g01[0];
    const float gi1 = (float)g01[1];
    const float gi2v = (float)g2p[0];
    if (i + 1 < NSTEP) giReg = gi2[(size_t)(i + 1) * 128];  // prefetch
    const float rg = fsig(gi0 + qred4(ah0a + ah0b) + bhh0);
    const float zg = fsig(gi1 + qred4(ah1a + ah1b) + bhh1);
    const float nn = ftanh_fast(gi2v + rg * (qred4(ah2a + ah2b) + bhh2));
    const float hg = (1.0f - zg) * nn + zg * h2e;
    float a = 0.f;
    if (i > 0) {
      const float y = qred4(ya + yb) + bias1;
      a = (oq < 64) ? ftanh_fast(y) : fsoftplus(y);
    }
    if (kq == 0) {
      sH[i & 1][oq] = (f16)hg;
      if (i > 0) sSa[oq] = (f16)a;
    }
    wg_barrier();  // 1: hg_i + a_{i-1} visible

    // ---- phase 2: h1n_{i-1} via W2 (regs); blend into h2_{i+1}
    float h2n;
    if (i == 0) {
      h2n = hg;
    } else {
      const uint4 da = *(const uint4*)&sSa[kb16];
      const uint4 db_ = *(const uint4*)&sSa[kb16 + 8];
      const uint4 ga = *(const uint4*)&sSa[64 + kb16];
      const uint4 gb = *(const uint4*)&sSa[64 + kb16 + 8];
      float fda = 0.f, fdb = 0.f, fga = 0.f, fgb = 0.f;
      DOT4R(fda, rW2d, 0, da);
      DOT4R(fdb, rW2d, 4, db_);
      DOT4R(fga, rW2g, 0, ga);
      DOT4R(fgb, rW2g, 4, gb);
      const float tdv = sTdv[i - 1];
      const float szs = sSq[i - 1] * sZsum[i - 1];
      const float h1n = hgPrev + tdv * (qred4(fda + fdb) + b2d) +
                        szs * (qred4(fga + fgb) + b2g);
      const float uu = sU[i];
      h2n = uu * hg + (1.0f - uu) * h1n;
    }
    if (kq == 0) sH2[oq] = (f16)h2n;
    h2e = h2n;
    hgPrev = hg;
    wg_barrier();  // 2: h2 visible for next iter
  }

  if (kq == 0) out[(size_t)b * H_LEN + oq] = h2e;
}

// ---- R5 fallback kernel (2 rows/WG; exact substeps; proven 956us)
__global__ __launch_bounds__(512, 2) void sde_fused_kernel(
    const float* __restrict__ inputs, const int* __restrict__ non_zero,
    const float* __restrict__ Wih, const float* __restrict__ Whh,
    const float* __restrict__ bih, const float* __restrict__ bhh,
    const float* __restrict__ dW1, const float* __restrict__ db1,
    const float* __restrict__ dW2, const float* __restrict__ db2,
    const float* __restrict__ gW1, const float* __restrict__ gb1,
    const float* __restrict__ gW2, const float* __restrict__ gb2,
    const float* __restrict__ wsTd, const float* __restrict__ wsC,
    const float* __restrict__ wsE, const f16* __restrict__ wsA,
    const f16* __restrict__ wsB, float* __restrict__ out) {
  __shared__ float sZ[NSTEP * NSUB * 2];
  __shared__ float sDt[NSTEP], sSq[NSTEP], sU[NSTEP];
  __shared__ __align__(16) f16 sX[2][H_LEN];
  __shared__ __align__(16) f16 sH2[2][H_LEN];
  __shared__ __align__(16) f16 sH[2][H_LEN];
  __shared__ __align__(16) f16 sActDB[2][2][H_LEN];
  __shared__ __align__(16) f16 sSa[2][H_LEN];

  const int t = threadIdx.x;
  const int kq = t & 3;
  const int oq = t >> 2;
  const int kb32 = kq * 32;
  const int kb16 = kq * 16;
  const int wg = blockIdx.x;
  const int b0 = wg * 2;

  const int La = non_zero[b0] - 1;
  const int Lb = non_zero[b0 + 1] - 1;
  const int Lmax = (La > Lb) ? La : Lb;

  for (int idx = t; idx < NSTEP * NSUB * 2; idx += 512) {
    const int r = idx & 1;
    const int is = idx >> 1;
    unsigned int f0 = 0u, f1 = (unsigned int)is;
    tf2x32(0u, 42u, f0, f1);
    unsigned int y0 = 0u, y1 = (unsigned int)(b0 + r);
    tf2x32(f0, f1, y0, y1);
    const unsigned int bits = y1;
    const float fl = __uint_as_float((bits >> 9) | 0x3F800000u) - 1.0f;
    const float lo = __uint_as_float(0xBF7FFFFFu);
    float u = fl * (1.0f - lo) + lo;
    u = fmaxf(lo, u);
    sZ[idx] = 1.41421356237f * erfinv_f32(u);
  }
  if (t < NSTEP) {
    const float td = wsTd[t];
    sDt[t] = td * 0.1f;
    sSq[t] = sqrtf(td * 0.1f);
    sU[t] = (t == 0) ? 1.0f : __expf(-wsTd[t - 1]);
  }

  f16x2 rWih[3][16], rWhh[3][16];
#pragma unroll
  for (int g = 0; g < 3; ++g) {
    const float* pi = Wih + (size_t)(oq + 128 * g) * 128 + kb32;
    const float* ph = Whh + (size_t)(oq + 128 * g) * 128 + kb32;
#pragma unroll
    for (int c = 0; c < 16; ++c) {
      f16x2 a;
      a[0] = (f16)pi[2 * c];
      a[1] = (f16)pi[2 * c + 1];
      rWih[g][c] = a;
      f16x2 b;
      b[0] = (f16)ph[2 * c];
      b[1] = (f16)ph[2 * c + 1];
      rWhh[g][c] = b;
    }
  }
  f16x2 rW1[16];
  {
    const float* p1 = (oq < 64) ? (dW1 + (size_t)oq * 128 + kb32)
                                : (gW1 + (size_t)(oq - 64) * 128 + kb32);
#pragma unroll
    for (int c = 0; c < 16; ++c) {
      f16x2 a;
      a[0] = (f16)p1[2 * c];
      a[1] = (f16)p1[2 * c + 1];
      rW1[c] = a;
    }
  }
  f16x2 wA[8], wB[8];
  {
    const f16x2* pA = (const f16x2*)wsA + oq * 32 + kq * 8;
    const f16x2* pB = (const f16x2*)wsB + oq * 32 + kq * 8;
#pragma unroll
    for (int c = 0; c < 8; ++c) {
      wA[c] = pA[c];
      wB[c] = pB[c];
    }
  }
  f16x2 rW2d[8], rW2g[8];
  {
    const float* pd = dW2 + (size_t)oq * 64 + kb16;
    const float* pg = gW2 + (size_t)oq * 64 + kb16;
#pragma unroll
    for (int c = 0; c < 8; ++c) {
      f16x2 a;
      a[0] = (f16)pd[2 * c];
      a[1] = (f16)pd[2 * c + 1];
      rW2d[c] = a;
      f16x2 b;
      b[0] = (f16)pg[2 * c];
      b[1] = (f16)pg[2 * c + 1];
      rW2g[c] = b;
    }
  }
  const float bias1 = (oq < 64) ? db1[oq] : gb1[oq - 64];
  const float bias2d = db2[oq], bias2g = gb2[oq];
  const float cB = wsC[oq], eB = wsE[oq];
  const float rB0 = bih[oq] + bhh[oq];
  const float rB1 = bih[oq + 128] + bhh[oq + 128];
  const float rBi2 = bih[oq + 256];
  const float rBh2 = bhh[oq + 256];

  float h2e[2] = {0.f, 0.f}, h1e[2] = {0.f, 0.f};
  if (kq < 2) sH2[kq][oq] = (f16)0.f;

  const int xr = (t >> 7) & 1;
  const int xe = t & 127;
  const float* xbase = inputs + (size_t)(b0 + xr) * H_LEN + xe;
  const size_t xstride = (size_t)B_LEN * H_LEN;
  float xreg = (t < 256) ? xbase[0] : 0.f;

  __syncthreads();

  for (int i = 0; i < Lmax; ++i) {
    if (t < 256) sX[xr][xe] = (f16)xreg;
    wg_barrier();
    if (t < 256 && (i + 1) < NSTEP) xreg = xbase[(size_t)(i + 1) * xstride];

    float ai0r0 = 0.f, ai0r1 = 0.f, ai1r0 = 0.f, ai1r1 = 0.f, ai2r0 = 0.f,
          ai2r1 = 0.f;
    float ah0r0 = 0.f, ah0r1 = 0.f, ah1r0 = 0.f, ah1r1 = 0.f, ah2r0 = 0.f,
          ah2r1 = 0.f;
#pragma unroll
    for (int c = 0; c < 4; ++c) {
      const uint4 xv0 = *(const uint4*)&sX[0][kb32 + c * 8];
      const uint4 xv1 = *(const uint4*)&sX[1][kb32 + c * 8];
      const uint4 hv0 = *(const uint4*)&sH2[0][kb32 + c * 8];
      const uint4 hv1 = *(const uint4*)&sH2[1][kb32 + c * 8];
      DOT4R(ai0r0, rWih[0], c * 4, xv0);
      DOT4R(ai0r1, rWih[0], c * 4, xv1);
      DOT4R(ai1r0, rWih[1], c * 4, xv0);
      DOT4R(ai1r1, rWih[1], c * 4, xv1);
      DOT4R(ai2r0, rWih[2], c * 4, xv0);
      DOT4R(ai2r1, rWih[2], c * 4, xv1);
      DOT4R(ah0r0, rWhh[0], c * 4, hv0);
      DOT4R(ah0r1, rWhh[0], c * 4, hv1);
      DOT4R(ah1r0, rWhh[1], c * 4, hv0);
      DOT4R(ah1r1, rWhh[1], c * 4, hv1);
      DOT4R(ah2r0, rWhh[2], c * 4, hv0);
      DOT4R(ah2r1, rWhh[2], c * 4, hv1);
    }
    const float sr0 = qred4(ai0r0 + ah0r0);
    const float sz0 = qred4(ai1r0 + ah1r0);
    const float sr1 = qred4(ai0r1 + ah0r1);
    const float sz1 = qred4(ai1r1 + ah1r1);
    const float in0 = qred4(ai2r0);
    const float in1 = qred4(ai2r1);
    const float hn0 = qred4(ah2r0);
    const float hn1 = qred4(ah2r1);

    float hg[2];
    {
      const float rg0 = fsig(sr0 + rB0);
      const float zg0 = fsig(sz0 + rB1);
      const float nn0 = ftanh_fast(in0 + rBi2 + rg0 * (hn0 + rBh2));
      hg[0] = (1.0f - zg0) * nn0 + zg0 * h2e[0];
      const float rg1 = fsig(sr1 + rB0);
      const float zg1 = fsig(sz1 + rB1);
      const float nn1 = ftanh_fast(in1 + rBi2 + rg1 * (hn1 + rBh2));
      hg[1] = (1.0f - zg1) * nn1 + zg1 * h2e[1];
    }
    if (kq < 2) sH[kq][oq] = (f16)hg[kq];
    wg_barrier();

    float y0 = 0.f, y1 = 0.f;
#pragma unroll
    for (int c = 0; c < 4; ++c) {
      const uint4 hv0 = *(const uint4*)&sH[0][kb32 + c * 8];
      const uint4 hv1 = *(const uint4*)&sH[1][kb32 + c * 8];
      DOT4R(y0, rW1, c * 4, hv0);
      DOT4R(y1, rW1, c * 4, hv1);
    }
    y0 = qred4(y0) + bias1;
    y1 = qred4(y1) + bias1;

    const float dt = sDt[i];
    const float sq = sSq[i];
    float sacc0 = 0.f, sacc1 = 0.f, zsum0 = 0.f, zsum1 = 0.f;

    for (int s = 0; s < NSUB; ++s) {
      const float2 zz = *(const float2*)&sZ[(i * NSUB + s) * 2];
      const float a0 = (oq < 64) ? ftanh_fast(y0) : fsoftplus(y0);
      const float a1 = (oq < 64) ? ftanh_fast(y1) : fsoftplus(y1);
      sacc0 += (oq < 64) ? a0 : zz.x * a0;
      sacc1 += (oq < 64) ? a1 : zz.y * a1;
      zsum0 += zz.x;
      zsum1 += zz.y;
      const int buf = s & 1;
      if (kq < 2) sActDB[buf][kq][oq] = (f16)(kq ? a1 : a0);
      wg_barrier();
      const uint4 t0a = *(const uint4*)&sActDB[buf][0][kb16];
      const uint4 t0b = *(const uint4*)&sActDB[buf][0][kb16 + 8];
      const uint4 s0a = *(const uint4*)&sActDB[buf][0][64 + kb16];
      const uint4 s0b = *(const uint4*)&sActDB[buf][0][64 + kb16 + 8];
      const uint4 t1a = *(const uint4*)&sActDB[buf][1][kb16];
      const uint4 t1b = *(const uint4*)&sActDB[buf][1][kb16 + 8];
      const uint4 s1a = *(const uint4*)&sActDB[buf][1][64 + kb16];
      const uint4 s1b = *(const uint4*)&sActDB[buf][1][64 + kb16 + 8];
      float dA0 = 0.f, dB0 = 0.f, dA1 = 0.f, dB1 = 0.f;
      DOT4R(dA0, wA, 0, t0a);
      DOT4R(dA0, wA, 4, t0b);
      DOT4R(dB0, wB, 0, s0a);
      DOT4R(dB0, wB, 4, s0b);
      DOT4R(dA1, wA, 0, t1a);
      DOT4R(dA1, wA, 4, t1b);
      DOT4R(dB1, wB, 0, s1a);
      DOT4R(dB1, wB, 4, s1b);
      const float redA0 = qred4(dA0);
      const float redB0 = qred4(dB0);
      const float redA1 = qred4(dA1);
      const float redB1 = qred4(dB1);
      y0 += dt * (redA0 + cB) + (sq * zz.x) * (redB0 + eB);
      y1 += dt * (redA1 + cB) + (sq * zz.y) * (redB1 + eB);
    }

    if (kq < 2) sSa[kq][oq] = (f16)(kq ? sacc1 : sacc0);
    wg_barrier();
    {
      const uint4 d0a = *(const uint4*)&sSa[0][kb16];
      const uint4 d0b = *(const uint4*)&sSa[0][kb16 + 8];
      const uint4 g0a = *(const uint4*)&sSa[0][64 + kb16];
      const uint4 g0b = *(const uint4*)&sSa[0][64 + kb16 + 8];
      const uint4 d1a = *(const uint4*)&sSa[1][kb16];
      const uint4 d1b = *(const uint4*)&sSa[1][kb16 + 8];
      const uint4 g1a = *(const uint4*)&sSa[1][64 + kb16];
      const uint4 g1b = *(const uint4*)&sSa[1][64 + kb16 + 8];
      float fd0 = 0.f, fg0 = 0.f, fd1 = 0.f, fg1 = 0.f;
      DOT4R(fd0, rW2d, 0, d0a);
      DOT4R(fd0, rW2d, 4, d0b);
      DOT4R(fg0, rW2g, 0, g0a);
      DOT4R(fg0, rW2g, 4, g0b);
      DOT4R(fd1, rW2d, 0, d1a);
      DOT4R(fd1, rW2d, 4, d1b);
      DOT4R(fg1, rW2g, 0, g1a);
      DOT4R(fg1, rW2g, 4, g1b);
      const float redD0 = qred4(fd0);
      const float redG0 = qred4(fg0);
      const float redD1 = qred4(fd1);
      const float redG1 = qred4(fg1);
      const float h1n0 = hg[0] + dt * redD0 + (dt * (float)NSUB) * bias2d +
                         sq * redG0 + (sq * zsum0) * bias2g;
      const float h1n1 = hg[1] + dt * redD1 + (dt * (float)NSUB) * bias2d +
                         sq * redG1 + (sq * zsum1) * bias2g;
      if (i < La) {
        h2e[0] = (i == 0) ? hg[0] : (sU[i] * hg[0] + (1.0f - sU[i]) * h1e[0]);
        h1e[0] = h1n0;
      }
      if (i < Lb) {
        h2e[1] = (i == 0) ? hg[1] : (sU[i] * hg[1] + (1.0f - sU[i]) * h1e[1]);
        h1e[1] = h1n1;
      }
    }
    if (kq < 2) sH2[kq][oq] = (f16)h2e[kq];
  }

  if (kq < 2) out[(size_t)(b0 + kq) * H_LEN + oq] = h2e[kq];
}

extern "C" void kernel_launch(void* const* d_in, const int* in_sizes, int n_in,
                              void* d_out, int out_size, void* d_ws,
                              size_t ws_size, hipStream_t stream) {
  (void)in_sizes;
  (void)n_in;
  (void)out_size;
  const float* inputs = (const float*)d_in[0];
  const float* times = (const float*)d_in[1];
  const int* non_zero = (const int*)d_in[2];
  const float* Wih = (const float*)d_in[3];
  const float* Whh = (const float*)d_in[4];
  const float* bih = (const float*)d_in[5];
  const float* bhh = (const float*)d_in[6];
  const float* dW1 = (const float*)d_in[7];
  const float* db1 = (const float*)d_in[8];
  const float* dW2 = (const float*)d_in[9];
  const float* db2 = (const float*)d_in[10];
  const float* gW1 = (const float*)d_in[11];
  const float* gb1 = (const float*)d_in[12];
  const float* gW2 = (const float*)d_in[13];
  const float* gb2 = (const float*)d_in[14];
  float* out = (float*)d_out;

  char* ws = (char*)d_ws;
  float* wsTd = (float*)ws;                // [0, 512)
  float* wsC = (float*)(ws + 512);         // [512, 1024)   (fallback only)
  float* wsE = (float*)(ws + 1024);        // [1024, 1536)  (fallback only)
  f16* wsA = (f16*)(ws + 1536);            // [1536, +16384)   (fallback only)
  f16* wsB = (f16*)(ws + 1536 + 16384);    // [17920, +16384)  (fallback only)
  int* wsPerm = (int*)(ws + 34816);        // [34816, +2048)
  f16* wsGi = (f16*)(ws + 36864);          // [36864, +66.6MB)
  const size_t GI_BYTES = (size_t)B_LEN * NSTEP * 128 * 4 * sizeof(f16);
  const size_t NEED = 36864 + GI_BYTES;

  hipLaunchKernelGGL(td_kernel, dim3(NSTEP), dim3(256), 0, stream, times,
                     non_zero, wsTd);
  if (ws_size >= NEED) {
    hipLaunchKernelGGL(rank_kernel, dim3(1), dim3(512), 0, stream, non_zero,
                       wsPerm);
    hipLaunchKernelGGL(sde_scan6, dim3(B_LEN), dim3(512), 0, stream, non_zero,
                       inputs, Wih, bih, Whh, bhh, dW1, db1, dW2, db2, gW1, gb1,
                       gW2, gb2, wsTd, wsGi, wsPerm, out);
  } else {
    hipLaunchKernelGGL(ab_kernel, dim3(128), dim3(128), 0, stream, dW1, gW1,
                       dW2, gW2, db2, gb2, wsC, wsE, wsA, wsB);
    hipLaunchKernelGGL(sde_fused_kernel, dim3(B_LEN / 2), dim3(512), 0, stream,
                       inputs, non_zero, Wih, Whh, bih, bhh, dW1, db1, dW2, db2,
                       gW1, gb1, gW2, gb2, wsTd, wsC, wsE, wsA, wsB, out);
  }
}

// Round 14
// 222.314 us; speedup vs baseline: 1.1327x; 1.1327x over previous
//
#include <hip/hip_runtime.h>
#include <cstdint>
#include <cstddef>

// R13: the untried quadrant = 2 barriers/step x 64 persistent weight regs.
// Scoreboard: R9 (3bar, 64 regs, Wc-LDS)=229; R10 (2bar, 12 b128/phase)=345;
// R11 (3bar, 80 regs)=249; R12 (2bar, 80 regs)=252. Diagnosis: >64 persistent
// f16x2 forces AGPR round-trips in the hot phase; piling >8 b128 in one phase
// serializes the LDS pipe. This round: defer the W2 half (not the y half):
//   phase 1 = GRU(4 b128) + W2*a_{i-1}(4 b128 sSa) + blend -> hg_i, h2_{i+1}
//             (sH2 double-buffered, write-no-race, no extra barrier)
//   phase 2 = y = Wc*hg from LDS (4 sWc + 4 sH b128) + act -> sSa
// Persistent regs: Whh 48 + W2 16 = 64 exactly; Wc stays in LDS (short phase).
// Phase 2 + barrier skipped on last step. Arithmetic identical to R9.
// Predicted: 195-215us (>=229 => revert to R9 and stop); absmax 9.765625e-4.

typedef _Float16 f16;
typedef _Float16 f16x2 __attribute__((ext_vector_type(2)));

#define NSTEP 127
#define NSUB 10
#define B_LEN 512
#define S_LEN 128
#define H_LEN 128

__device__ __forceinline__ float dot2acc(f16x2 a, f16x2 b, float c) {
  return __builtin_amdgcn_fdot2(a, b, c, false);
}
__device__ __forceinline__ f16x2 bchalf(unsigned int u) {
  return __builtin_bit_cast(f16x2, u);
}

__device__ __forceinline__ float qred4(float v) {
  int a = __builtin_bit_cast(int, v);
  int b = __builtin_amdgcn_update_dpp(0, a, 0xB1, 0xF, 0xF, true);  // xor 1
  float v1 = v + __builtin_bit_cast(float, b);
  int c = __builtin_bit_cast(int, v1);
  int d = __builtin_amdgcn_update_dpp(0, c, 0x4E, 0xF, 0xF, true);  // xor 2
  return v1 + __builtin_bit_cast(float, d);
}

__device__ __forceinline__ void wg_barrier() {
  asm volatile("s_waitcnt lgkmcnt(0)\n\ts_barrier" ::: "memory");
}

#define DOT4R(acc, wr, base, dv)                          \
  do {                                                    \
    acc = dot2acc((wr)[(base) + 0], bchalf((dv).x), acc); \
    acc = dot2acc((wr)[(base) + 1], bchalf((dv).y), acc); \
    acc = dot2acc((wr)[(base) + 2], bchalf((dv).z), acc); \
    acc = dot2acc((wr)[(base) + 3], bchalf((dv).w), acc); \
  } while (0)

#define DOT4V(acc, wv, hv)                              \
  do {                                                  \
    acc = dot2acc(bchalf((wv).x), bchalf((hv).x), acc); \
    acc = dot2acc(bchalf((wv).y), bchalf((hv).y), acc); \
    acc = dot2acc(bchalf((wv).z), bchalf((hv).z), acc); \
    acc = dot2acc(bchalf((wv).w), bchalf((hv).w), acc); \
  } while (0)

// JAX threefry2x32 (20 rounds) -- bit-exact (verified: absmax <=2e-3).
__device__ __forceinline__ void tf2x32(unsigned int k0, unsigned int k1,
                                       unsigned int& x0, unsigned int& x1) {
  unsigned int ks[3] = {k0, k1, k0 ^ k1 ^ 0x1BD11BDAu};
  x0 += ks[0];
  x1 += ks[1];
  const int R[2][4] = {{13, 15, 26, 6}, {17, 29, 16, 24}};
#pragma unroll
  for (int g = 0; g < 5; ++g) {
#pragma unroll
    for (int j = 0; j < 4; ++j) {
      const int r = R[g & 1][j];
      x0 += x1;
      x1 = (x1 << r) | (x1 >> (32 - r));
      x1 ^= x0;
    }
    x0 += ks[(g + 1) % 3];
    x1 += ks[(g + 2) % 3] + (unsigned int)(g + 1);
  }
}

__device__ __forceinline__ float erfinv_f32(float x) {
  float w = -log1pf(-x * x);
  float p;
  if (w < 5.0f) {
    w = w - 2.5f;
    p = 2.81022636e-08f;
    p = fmaf(p, w, 3.43273939e-07f);
    p = fmaf(p, w, -3.5233877e-06f);
    p = fmaf(p, w, -4.39150654e-06f);
    p = fmaf(p, w, 0.00021858087f);
    p = fmaf(p, w, -0.00125372503f);
    p = fmaf(p, w, -0.00417768164f);
    p = fmaf(p, w, 0.246640727f);
    p = fmaf(p, w, 1.50140941f);
  } else {
    w = sqrtf(w) - 3.0f;
    p = -0.000200214257f;
    p = fmaf(p, w, 0.000100950558f);
    p = fmaf(p, w, 0.00134934322f);
    p = fmaf(p, w, -0.00367342844f);
    p = fmaf(p, w, 0.00573950773f);
    p = fmaf(p, w, -0.0076224613f);
    p = fmaf(p, w, 0.00943887047f);
    p = fmaf(p, w, 1.00167406f);
    p = fmaf(p, w, 2.83297682f);
  }
  return p * x;
}

__device__ __forceinline__ float frcp(float x) {
  return __builtin_amdgcn_rcpf(x);
}
__device__ __forceinline__ float fsig(float x) {
  return frcp(1.0f + __expf(-x));
}
__device__ __forceinline__ float ftanh_fast(float x) {
  return 1.0f - 2.0f * frcp(__expf(2.0f * x) + 1.0f);
}
__device__ __forceinline__ float fsoftplus(float x) {
  return fmaxf(x, 0.0f) + __logf(1.0f + __expf(-fabsf(x)));
}

// ---- td precompute
__global__ __launch_bounds__(256) void td_kernel(
    const float* __restrict__ times, const int* __restrict__ non_zero,
    float* __restrict__ wsTd) {
  __shared__ float sA[256], sB[256];
  __shared__ int sC[256];
  const int i = blockIdx.x;
  const int t = threadIdx.x;
  float s1 = 0.f, s2 = 0.f;
  int c = 0;
  for (int b = t; b < B_LEN; b += 256) {
    const int nz = non_zero[b];
    const float t1 = times[b * S_LEN + i + 1];
    const bool v = (i < nz - 1) && (t1 != 0.0f);
    if (v) {
      c += 1;
      s1 += times[b * S_LEN + i];
      s2 += t1;
    }
  }
  sA[t] = s1;
  sB[t] = s2;
  sC[t] = c;
  __syncthreads();
  for (int o = 128; o > 0; o >>= 1) {
    if (t < o) {
      sA[t] += sA[t + o];
      sB[t] += sB[t + o];
      sC[t] += sC[t + o];
    }
    __syncthreads();
  }
  if (t == 0) {
    const float cnt = (float)((sC[0] < 1) ? 1 : sC[0]);
    const float ts = sA[0] / cnt * 0.02f;
    const float te = sB[0] / cnt * 0.02f;
    wsTd[i] = (te == ts) ? 1.0f : (te - ts);
  }
}

// ---- A/B/c/e precompute (only needed by the R5 fallback kernel)
__global__ __launch_bounds__(128) void ab_kernel(
    const float* __restrict__ dW1, const float* __restrict__ gW1,
    const float* __restrict__ dW2, const float* __restrict__ gW2,
    const float* __restrict__ db2, const float* __restrict__ gb2,
    float* __restrict__ wsC, float* __restrict__ wsE, f16* __restrict__ wsA,
    f16* __restrict__ wsB) {
  __shared__ float sWc[128];
  const int o = blockIdx.x;
  const int j = threadIdx.x;
  sWc[j] = (o < 64) ? dW1[o * 128 + j] : gW1[(o - 64) * 128 + j];
  __syncthreads();
  float acc = 0.f;
  if (j < 64) {
    for (int m = 0; m < 128; ++m) acc += sWc[m] * dW2[m * 64 + j];
    wsA[o * 64 + j] = (f16)acc;
  } else {
    const int jj = j - 64;
    for (int m = 0; m < 128; ++m) acc += sWc[m] * gW2[m * 64 + jj];
    wsB[o * 64 + jj] = (f16)acc;
  }
  if (j == 0) {
    float cc = 0.f;
    for (int m = 0; m < 128; ++m) cc += sWc[m] * db2[m];
    wsC[o] = cc;
  }
  if (j == 1) {
    float ee = 0.f;
    for (int m = 0; m < 128; ++m) ee += sWc[m] * gb2[m];
    wsE[o] = ee;
  }
}

// ---- rank permutation: longest-with-shortest pairing.
__global__ __launch_bounds__(512) void rank_kernel(
    const int* __restrict__ non_zero, int* __restrict__ wsPerm) {
  __shared__ int sL[512];
  const int t = threadIdx.x;
  sL[t] = non_zero[t];
  __syncthreads();
  const int Li = sL[t];
  int r = 0;
  for (int j = 0; j < 512; ++j) {
    const int Lj = sL[j];
    r += (Lj > Li) || (Lj == Li && j < t);
  }
  const int g = (r < 256) ? r : (767 - r);
  wsPerm[g] = t;
}

// ---- main scan: 1 row/WG, gi prologue fused, 2 barriers/step, W2-deferred,
//      64 persistent weight regs (Whh+W2); Wc in LDS (swizzled).
__global__ __launch_bounds__(512, 4) void sde_scan7(
    const int* __restrict__ non_zero, const float* __restrict__ inputs,
    const float* __restrict__ Wih, const float* __restrict__ bih,
    const float* __restrict__ Whh, const float* __restrict__ bhh,
    const float* __restrict__ dW1, const float* __restrict__ db1,
    const float* __restrict__ dW2, const float* __restrict__ db2,
    const float* __restrict__ gW1, const float* __restrict__ gb1,
    const float* __restrict__ gW2, const float* __restrict__ gb2,
    const float* __restrict__ wsTd, f16* __restrict__ wsGi,
    const int* __restrict__ wsPerm, float* __restrict__ out) {
  __shared__ __align__(16) f16 sWc[128 * 128];      // 32KB swizzled y-init W
  __shared__ __align__(16) f16 sXall[NSTEP * 128];  // 32.5KB all x for row
  __shared__ f16 sZ[NSTEP * NSUB];
  __shared__ float sTdv[NSTEP], sSq[NSTEP], sU[NSTEP], sZsum[NSTEP];
  __shared__ __align__(16) f16 sH2[2][H_LEN];  // dbuf: h2_i / h2_{i+1}
  __shared__ __align__(16) f16 sH[H_LEN], sSa[H_LEN];

  const int t = threadIdx.x;
  const int kq = t & 3;
  const int oq = t >> 2;
  const int kb32 = kq * 32;
  const int kb16 = kq * 16;
  const int b = wsPerm[blockIdx.x];  // permuted row
  const int L = non_zero[b] - 1;

  // noise (bit-stream identical to R0-R12; only per-step sums feed the model)
  for (int idx = t; idx < NSTEP * NSUB; idx += 512) {
    unsigned int f0 = 0u, f1 = (unsigned int)idx;
    tf2x32(0u, 42u, f0, f1);
    unsigned int y0 = 0u, y1 = (unsigned int)b;
    tf2x32(f0, f1, y0, y1);
    const unsigned int bits = y1;
    const float fl = __uint_as_float((bits >> 9) | 0x3F800000u) - 1.0f;
    const float lo = __uint_as_float(0xBF7FFFFFu);
    float u = fl * (1.0f - lo) + lo;
    u = fmaxf(lo, u);
    sZ[idx] = (f16)(1.41421356237f * erfinv_f32(u));
  }
  if (t < NSTEP) {
    const float td = wsTd[t];
    sTdv[t] = td;
    sSq[t] = sqrtf(td * 0.1f);
    sU[t] = (t == 0) ? 1.0f : __expf(-wsTd[t - 1]);
  }
  // bulk x staging: all 127 steps of this row, f32 -> f16
  for (int idx = t; idx < NSTEP * 128; idx += 512) {
    const int i = idx >> 7, h = idx & 127;
    sXall[idx] = (f16)inputs[((size_t)i * B_LEN + b) * H_LEN + h];
  }
  // Wc staging, swizzled 16B units: 128 rows x 16 units = 2048 (full matrix!)
  for (int g = t; g < 2048; g += 512) {
    const int row = g >> 4, u = g & 15;
    const float* src = ((row < 64) ? dW1 + (size_t)row * 128
                                   : gW1 + (size_t)(row - 64) * 128) +
                       u * 8;
    f16 tmp[8];
#pragma unroll
    for (int c = 0; c < 8; ++c) tmp[c] = (f16)src[c];
    *(uint4*)&sWc[row * 128 + ((u ^ (row & 15)) * 8)] = *(const uint4*)tmp;
  }
  if (kq == 0) sH2[0][oq] = (f16)0.f;
  __syncthreads();
  if (t < NSTEP) {
    float s = 0.f;
#pragma unroll
    for (int k = 0; k < NSUB; ++k) s += (float)sZ[t * NSUB + k];
    sZsum[t] = s;
  }

  // ---- gi prologue: rW holds Wih slices now, Whh later (same registers)
  f16x2 rW[3][16];
#pragma unroll
  for (int g = 0; g < 3; ++g) {
    const float* pi = Wih + (size_t)(oq + 128 * g) * 128 + kb32;
#pragma unroll
    for (int c = 0; c < 16; ++c) {
      f16x2 a;
      a[0] = (f16)pi[2 * c];
      a[1] = (f16)pi[2 * c + 1];
      rW[g][c] = a;
    }
  }
  {
    const float bi0 = bih[oq];
    const float bi1 = bih[oq + 128];
    const float bi2 = bih[oq + 256];
    uint2* giOut = (uint2*)wsGi + (size_t)b * NSTEP * 128 + oq;
    for (int i = 0; i < NSTEP; ++i) {
      float a0 = 0.f, a1 = 0.f, a2 = 0.f;
#pragma unroll
      for (int c = 0; c < 4; ++c) {
        const uint4 xv = *(const uint4*)&sXall[i * 128 + kb32 + c * 8];
        DOT4R(a0, rW[0], c * 4, xv);
        DOT4R(a1, rW[1], c * 4, xv);
        DOT4R(a2, rW[2], c * 4, xv);
      }
      const float g0 = qred4(a0) + bi0;
      const float g1 = qred4(a1) + bi1;
      const float g2 = qred4(a2) + bi2;
      if (kq == 0) {
        union {
          f16 h[4];
          uint2 u2;
        } pk;
        pk.h[0] = (f16)g0;
        pk.h[1] = (f16)g1;
        pk.h[2] = (f16)g2;
        pk.h[3] = (f16)0.f;
        giOut[(size_t)i * 128] = pk.u2;
      }
    }
  }
  __syncthreads();  // full drain: gi stores visible to all lanes

  // ---- reload rW with Whh; load W2 slices (persistent = 64 f16x2 total)
#pragma unroll
  for (int g = 0; g < 3; ++g) {
    const float* ph = Whh + (size_t)(oq + 128 * g) * 128 + kb32;
#pragma unroll
    for (int c = 0; c < 16; ++c) {
      f16x2 bb;
      bb[0] = (f16)ph[2 * c];
      bb[1] = (f16)ph[2 * c + 1];
      rW[g][c] = bb;
    }
  }
  f16x2 rW2d[8], rW2g[8];
  {
    const float* pd = dW2 + (size_t)oq * 64 + kb16;
    const float* pg = gW2 + (size_t)oq * 64 + kb16;
#pragma unroll
    for (int c = 0; c < 8; ++c) {
      f16x2 a;
      a[0] = (f16)pd[2 * c];
      a[1] = (f16)pd[2 * c + 1];
      rW2d[c] = a;
      f16x2 bb;
      bb[0] = (f16)pg[2 * c];
      bb[1] = (f16)pg[2 * c + 1];
      rW2g[c] = bb;
    }
  }
  const float bhh0 = bhh[oq];
  const float bhh1 = bhh[oq + 128];
  const float bhh2 = bhh[oq + 256];
  const float bias1 = (oq < 64) ? db1[oq] : gb1[oq - 64];
  const float b2d = db2[oq], b2g = gb2[oq];

  float h2e = 0.f, hgPrev = 0.f;
  const uint2* gi2 = (const uint2*)wsGi + (size_t)b * NSTEP * 128 + oq;
  uint2 giReg = gi2[0];

  for (int i = 0; i < L; ++i) {
    // ---- phase 1: GRU(Whh x h2_i) + W2 x a_{i-1} + blend (8 b128 total)
    const f16* sH2c = sH2[i & 1];
    float ah0a = 0.f, ah1a = 0.f, ah2a = 0.f;
    float ah0b = 0.f, ah1b = 0.f, ah2b = 0.f;
    {
      const uint4 hv0 = *(const uint4*)&sH2c[kb32];
      const uint4 hv1 = *(const uint4*)&sH2c[kb32 + 8];
      const uint4 hv2 = *(const uint4*)&sH2c[kb32 + 16];
      const uint4 hv3 = *(const uint4*)&sH2c[kb32 + 24];
      DOT4R(ah0a, rW[0], 0, hv0);
      DOT4R(ah0a, rW[0], 4, hv1);
      DOT4R(ah0b, rW[0], 8, hv2);
      DOT4R(ah0b, rW[0], 12, hv3);
      DOT4R(ah1a, rW[1], 0, hv0);
      DOT4R(ah1a, rW[1], 4, hv1);
      DOT4R(ah1b, rW[1], 8, hv2);
      DOT4R(ah1b, rW[1], 12, hv3);
      DOT4R(ah2a, rW[2], 0, hv0);
      DOT4R(ah2a, rW[2], 4, hv1);
      DOT4R(ah2b, rW[2], 8, hv2);
      DOT4R(ah2b, rW[2], 12, hv3);
    }
    float fda = 0.f, fdb = 0.f, fga = 0.f, fgb = 0.f;
    if (i > 0) {
      const uint4 da = *(const uint4*)&sSa[kb16];
      const uint4 db_ = *(const uint4*)&sSa[kb16 + 8];
      const uint4 ga = *(const uint4*)&sSa[64 + kb16];
      const uint4 gb = *(const uint4*)&sSa[64 + kb16 + 8];
      DOT4R(fda, rW2d, 0, da);
      DOT4R(fdb, rW2d, 4, db_);
      DOT4R(fga, rW2g, 0, ga);
      DOT4R(fgb, rW2g, 4, gb);
    }
    const f16x2 g01 = bchalf(giReg.x);
    const f16x2 g2p = bchalf(giReg.y);
    const float gi0 = (float)g01[0];
    const float gi1 = (float)g01[1];
    const float gi2v = (float)g2p[0];
    if (i + 1 < NSTEP) giReg = gi2[(size_t)(i + 1) * 128];  // prefetch
    const float rg = fsig(gi0 + qred4(ah0a + ah0b) + bhh0);
    const float zg = fsig(gi1 + qred4(ah1a + ah1b) + bhh1);
    const float nn = ftanh_fast(gi2v + rg * (qred4(ah2a + ah2b) + bhh2));
    const float hg = (1.0f - zg) * nn + zg * h2e;
    float h2n;
    if (i == 0) {
      h2n = hg;
    } else {
      const float tdv = sTdv[i - 1];
      const float szs = sSq[i - 1] * sZsum[i - 1];
      const float h1n = hgPrev + tdv * (qred4(fda + fdb) + b2d) +
                        szs * (qred4(fga + fgb) + b2g);
      const float uu = sU[i];
      h2n = uu * hg + (1.0f - uu) * h1n;
    }
    if (kq == 0) {
      sH[oq] = (f16)hg;
      sH2[(i + 1) & 1][oq] = (f16)h2n;  // other buffer: no read/write race
    }
    h2e = h2n;
    hgPrev = hg;
    wg_barrier();  // 1: hg + h2_{i+1} visible

    // ---- phase 2 (skipped on last step): y = Wc x hg (LDS), a -> sSa
    if (i + 1 < L) {
      float ya = 0.f, yb = 0.f;
      {
        const int u0 = kq * 4;
        const uint4 wv0 = *(const uint4*)&sWc[oq * 128 + ((u0 ^ (oq & 15)) * 8)];
        const uint4 wv1 =
            *(const uint4*)&sWc[oq * 128 + (((u0 + 1) ^ (oq & 15)) * 8)];
        const uint4 wv2 =
            *(const uint4*)&sWc[oq * 128 + (((u0 + 2) ^ (oq & 15)) * 8)];
        const uint4 wv3 =
            *(const uint4*)&sWc[oq * 128 + (((u0 + 3) ^ (oq & 15)) * 8)];
        const uint4 hv0 = *(const uint4*)&sH[u0 * 8];
        const uint4 hv1 = *(const uint4*)&sH[u0 * 8 + 8];
        const uint4 hv2 = *(const uint4*)&sH[u0 * 8 + 16];
        const uint4 hv3 = *(const uint4*)&sH[u0 * 8 + 24];
        DOT4V(ya, wv0, hv0);
        DOT4V(ya, wv1, hv1);
        DOT4V(yb, wv2, hv2);
        DOT4V(yb, wv3, hv3);
      }
      const float y = qred4(ya + yb) + bias1;
      const float a = (oq < 64) ? ftanh_fast(y) : fsoftplus(y);
      if (kq == 0) sSa[oq] = (f16)a;
      wg_barrier();  // 2: a visible for next step's phase 1
    }
  }

  if (kq == 0) out[(size_t)b * H_LEN + oq] = h2e;
}

// ---- R5 fallback kernel (2 rows/WG; exact substeps; proven 956us)
__global__ __launch_bounds__(512, 2) void sde_fused_kernel(
    const float* __restrict__ inputs, const int* __restrict__ non_zero,
    const float* __restrict__ Wih, const float* __restrict__ Whh,
    const float* __restrict__ bih, const float* __restrict__ bhh,
    const float* __restrict__ dW1, const float* __restrict__ db1,
    const float* __restrict__ dW2, const float* __restrict__ db2,
    const float* __restrict__ gW1, const float* __restrict__ gb1,
    const float* __restrict__ gW2, const float* __restrict__ gb2,
    const float* __restrict__ wsTd, const float* __restrict__ wsC,
    const float* __restrict__ wsE, const f16* __restrict__ wsA,
    const f16* __restrict__ wsB, float* __restrict__ out) {
  __shared__ float sZ[NSTEP * NSUB * 2];
  __shared__ float sDt[NSTEP], sSq[NSTEP], sU[NSTEP];
  __shared__ __align__(16) f16 sX[2][H_LEN];
  __shared__ __align__(16) f16 sH2[2][H_LEN];
  __shared__ __align__(16) f16 sH[2][H_LEN];
  __shared__ __align__(16) f16 sActDB[2][2][H_LEN];
  __shared__ __align__(16) f16 sSa[2][H_LEN];

  const int t = threadIdx.x;
  const int kq = t & 3;
  const int oq = t >> 2;
  const int kb32 = kq * 32;
  const int kb16 = kq * 16;
  const int wg = blockIdx.x;
  const int b0 = wg * 2;

  const int La = non_zero[b0] - 1;
  const int Lb = non_zero[b0 + 1] - 1;
  const int Lmax = (La > Lb) ? La : Lb;

  for (int idx = t; idx < NSTEP * NSUB * 2; idx += 512) {
    const int r = idx & 1;
    const int is = idx >> 1;
    unsigned int f0 = 0u, f1 = (unsigned int)is;
    tf2x32(0u, 42u, f0, f1);
    unsigned int y0 = 0u, y1 = (unsigned int)(b0 + r);
    tf2x32(f0, f1, y0, y1);
    const unsigned int bits = y1;
    const float fl = __uint_as_float((bits >> 9) | 0x3F800000u) - 1.0f;
    const float lo = __uint_as_float(0xBF7FFFFFu);
    float u = fl * (1.0f - lo) + lo;
    u = fmaxf(lo, u);
    sZ[idx] = 1.41421356237f * erfinv_f32(u);
  }
  if (t < NSTEP) {
    const float td = wsTd[t];
    sDt[t] = td * 0.1f;
    sSq[t] = sqrtf(td * 0.1f);
    sU[t] = (t == 0) ? 1.0f : __expf(-wsTd[t - 1]);
  }

  f16x2 rWih[3][16], rWhh[3][16];
#pragma unroll
  for (int g = 0; g < 3; ++g) {
    const float* pi = Wih + (size_t)(oq + 128 * g) * 128 + kb32;
    const float* ph = Whh + (size_t)(oq + 128 * g) * 128 + kb32;
#pragma unroll
    for (int c = 0; c < 16; ++c) {
      f16x2 a;
      a[0] = (f16)pi[2 * c];
      a[1] = (f16)pi[2 * c + 1];
      rWih[g][c] = a;
      f16x2 b;
      b[0] = (f16)ph[2 * c];
      b[1] = (f16)ph[2 * c + 1];
      rWhh[g][c] = b;
    }
  }
  f16x2 rW1[16];
  {
    const float* p1 = (oq < 64) ? (dW1 + (size_t)oq * 128 + kb32)
                                : (gW1 + (size_t)(oq - 64) * 128 + kb32);
#pragma unroll
    for (int c = 0; c < 16; ++c) {
      f16x2 a;
      a[0] = (f16)p1[2 * c];
      a[1] = (f16)p1[2 * c + 1];
      rW1[c] = a;
    }
  }
  f16x2 wA[8], wB[8];
  {
    const f16x2* pA = (const f16x2*)wsA + oq * 32 + kq * 8;
    const f16x2* pB = (const f16x2*)wsB + oq * 32 + kq * 8;
#pragma unroll
    for (int c = 0; c < 8; ++c) {
      wA[c] = pA[c];
      wB[c] = pB[c];
    }
  }
  f16x2 rW2d[8], rW2g[8];
  {
    const float* pd = dW2 + (size_t)oq * 64 + kb16;
    const float* pg = gW2 + (size_t)oq * 64 + kb16;
#pragma unroll
    for (int c = 0; c < 8; ++c) {
      f16x2 a;
      a[0] = (f16)pd[2 * c];
      a[1] = (f16)pd[2 * c + 1];
      rW2d[c] = a;
      f16x2 b;
      b[0] = (f16)pg[2 * c];
      b[1] = (f16)pg[2 * c + 1];
      rW2g[c] = b;
    }
  }
  const float bias1 = (oq < 64) ? db1[oq] : gb1[oq - 64];
  const float bias2d = db2[oq], bias2g = gb2[oq];
  const float cB = wsC[oq], eB = wsE[oq];
  const float rB0 = bih[oq] + bhh[oq];
  const float rB1 = bih[oq + 128] + bhh[oq + 128];
  const float rBi2 = bih[oq + 256];
  const float rBh2 = bhh[oq + 256];

  float h2e[2] = {0.f, 0.f}, h1e[2] = {0.f, 0.f};
  if (kq < 2) sH2[kq][oq] = (f16)0.f;

  const int xr = (t >> 7) & 1;
  const int xe = t & 127;
  const float* xbase = inputs + (size_t)(b0 + xr) * H_LEN + xe;
  const size_t xstride = (size_t)B_LEN * H_LEN;
  float xreg = (t < 256) ? xbase[0] : 0.f;

  __syncthreads();

  for (int i = 0; i < Lmax; ++i) {
    if (t < 256) sX[xr][xe] = (f16)xreg;
    wg_barrier();
    if (t < 256 && (i + 1) < NSTEP) xreg = xbase[(size_t)(i + 1) * xstride];

    float ai0r0 = 0.f, ai0r1 = 0.f, ai1r0 = 0.f, ai1r1 = 0.f, ai2r0 = 0.f,
          ai2r1 = 0.f;
    float ah0r0 = 0.f, ah0r1 = 0.f, ah1r0 = 0.f, ah1r1 = 0.f, ah2r0 = 0.f,
          ah2r1 = 0.f;
#pragma unroll
    for (int c = 0; c < 4; ++c) {
      const uint4 xv0 = *(const uint4*)&sX[0][kb32 + c * 8];
      const uint4 xv1 = *(const uint4*)&sX[1][kb32 + c * 8];
      const uint4 hv0 = *(const uint4*)&sH2[0][kb32 + c * 8];
      const uint4 hv1 = *(const uint4*)&sH2[1][kb32 + c * 8];
      DOT4R(ai0r0, rWih[0], c * 4, xv0);
      DOT4R(ai0r1, rWih[0], c * 4, xv1);
      DOT4R(ai1r0, rWih[1], c * 4, xv0);
      DOT4R(ai1r1, rWih[1], c * 4, xv1);
      DOT4R(ai2r0, rWih[2], c * 4, xv0);
      DOT4R(ai2r1, rWih[2], c * 4, xv1);
      DOT4R(ah0r0, rWhh[0], c * 4, hv0);
      DOT4R(ah0r1, rWhh[0], c * 4, hv1);
      DOT4R(ah1r0, rWhh[1], c * 4, hv0);
      DOT4R(ah1r1, rWhh[1], c * 4, hv1);
      DOT4R(ah2r0, rWhh[2], c * 4, hv0);
      DOT4R(ah2r1, rWhh[2], c * 4, hv1);
    }
    const float sr0 = qred4(ai0r0 + ah0r0);
    const float sz0 = qred4(ai1r0 + ah1r0);
    const float sr1 = qred4(ai0r1 + ah0r1);
    const float sz1 = qred4(ai1r1 + ah1r1);
    const float in0 = qred4(ai2r0);
    const float in1 = qred4(ai2r1);
    const float hn0 = qred4(ah2r0);
    const float hn1 = qred4(ah2r1);

    float hg[2];
    {
      const float rg0 = fsig(sr0 + rB0);
      const float zg0 = fsig(sz0 + rB1);
      const float nn0 = ftanh_fast(in0 + rBi2 + rg0 * (hn0 + rBh2));
      hg[0] = (1.0f - zg0) * nn0 + zg0 * h2e[0];
      const float rg1 = fsig(sr1 + rB0);
      const float zg1 = fsig(sz1 + rB1);
      const float nn1 = ftanh_fast(in1 + rBi2 + rg1 * (hn1 + rBh2));
      hg[1] = (1.0f - zg1) * nn1 + zg1 * h2e[1];
    }
    if (kq < 2) sH[kq][oq] = (f16)hg[kq];
    wg_barrier();

    float y0 = 0.f, y1 = 0.f;
#pragma unroll
    for (int c = 0; c < 4; ++c) {
      const uint4 hv0 = *(const uint4*)&sH[0][kb32 + c * 8];
      const uint4 hv1 = *(const uint4*)&sH[1][kb32 + c * 8];
      DOT4R(y0, rW1, c * 4, hv0);
      DOT4R(y1, rW1, c * 4, hv1);
    }
    y0 = qred4(y0) + bias1;
    y1 = qred4(y1) + bias1;

    const float dt = sDt[i];
    const float sq = sSq[i];
    float sacc0 = 0.f, sacc1 = 0.f, zsum0 = 0.f, zsum1 = 0.f;

    for (int s = 0; s < NSUB; ++s) {
      const float2 zz = *(const float2*)&sZ[(i * NSUB + s) * 2];
      const float a0 = (oq < 64) ? ftanh_fast(y0) : fsoftplus(y0);
      const float a1 = (oq < 64) ? ftanh_fast(y1) : fsoftplus(y1);
      sacc0 += (oq < 64) ? a0 : zz.x * a0;
      sacc1 += (oq < 64) ? a1 : zz.y * a1;
      zsum0 += zz.x;
      zsum1 += zz.y;
      const int buf = s & 1;
      if (kq < 2) sActDB[buf][kq][oq] = (f16)(kq ? a1 : a0);
      wg_barrier();
      const uint4 t0a = *(const uint4*)&sActDB[buf][0][kb16];
      const uint4 t0b = *(const uint4*)&sActDB[buf][0][kb16 + 8];
      const uint4 s0a = *(const uint4*)&sActDB[buf][0][64 + kb16];
      const uint4 s0b = *(const uint4*)&sActDB[buf][0][64 + kb16 + 8];
      const uint4 t1a = *(const uint4*)&sActDB[buf][1][kb16];
      const uint4 t1b = *(const uint4*)&sActDB[buf][1][kb16 + 8];
      const uint4 s1a = *(const uint4*)&sActDB[buf][1][64 + kb16];
      const uint4 s1b = *(const uint4*)&sActDB[buf][1][64 + kb16 + 8];
      float dA0 = 0.f, dB0 = 0.f, dA1 = 0.f, dB1 = 0.f;
      DOT4R(dA0, wA, 0, t0a);
      DOT4R(dA0, wA, 4, t0b);
      DOT4R(dB0, wB, 0, s0a);
      DOT4R(dB0, wB, 4, s0b);
      DOT4R(dA1, wA, 0, t1a);
      DOT4R(dA1, wA, 4, t1b);
      DOT4R(dB1, wB, 0, s1a);
      DOT4R(dB1, wB, 4, s1b);
      const float redA0 = qred4(dA0);
      const float redB0 = qred4(dB0);
      const float redA1 = qred4(dA1);
      const float redB1 = qred4(dB1);
      y0 += dt * (redA0 + cB) + (sq * zz.x) * (redB0 + eB);
      y1 += dt * (redA1 + cB) + (sq * zz.y) * (redB1 + eB);
    }

    if (kq < 2) sSa[kq][oq] = (f16)(kq ? sacc1 : sacc0);
    wg_barrier();
    {
      const uint4 d0a = *(const uint4*)&sSa[0][kb16];
      const uint4 d0b = *(const uint4*)&sSa[0][kb16 + 8];
      const uint4 g0a = *(const uint4*)&sSa[0][64 + kb16];
      const uint4 g0b = *(const uint4*)&sSa[0][64 + kb16 + 8];
      const uint4 d1a = *(const uint4*)&sSa[1][kb16];
      const uint4 d1b = *(const uint4*)&sSa[1][kb16 + 8];
      const uint4 g1a = *(const uint4*)&sSa[1][64 + kb16];
      const uint4 g1b = *(const uint4*)&sSa[1][64 + kb16 + 8];
      float fd0 = 0.f, fg0 = 0.f, fd1 = 0.f, fg1 = 0.f;
      DOT4R(fd0, rW2d, 0, d0a);
      DOT4R(fd0, rW2d, 4, d0b);
      DOT4R(fg0, rW2g, 0, g0a);
      DOT4R(fg0, rW2g, 4, g0b);
      DOT4R(fd1, rW2d, 0, d1a);
      DOT4R(fd1, rW2d, 4, d1b);
      DOT4R(fg1, rW2g, 0, g1a);
      DOT4R(fg1, rW2g, 4, g1b);
      const float redD0 = qred4(fd0);
      const float redG0 = qred4(fg0);
      const float redD1 = qred4(fd1);
      const float redG1 = qred4(fg1);
      const float h1n0 = hg[0] + dt * redD0 + (dt * (float)NSUB) * bias2d +
                         sq * redG0 + (sq * zsum0) * bias2g;
      const float h1n1 = hg[1] + dt * redD1 + (dt * (float)NSUB) * bias2d +
                         sq * redG1 + (sq * zsum1) * bias2g;
      if (i < La) {
        h2e[0] = (i == 0) ? hg[0] : (sU[i] * hg[0] + (1.0f - sU[i]) * h1e[0]);
        h1e[0] = h1n0;
      }
      if (i < Lb) {
        h2e[1] = (i == 0) ? hg[1] : (sU[i] * hg[1] + (1.0f - sU[i]) * h1e[1]);
        h1e[1] = h1n1;
      }
    }
    if (kq < 2) sH2[kq][oq] = (f16)h2e[kq];
  }

  if (kq < 2) out[(size_t)(b0 + kq) * H_LEN + oq] = h2e[kq];
}

extern "C" void kernel_launch(void* const* d_in, const int* in_sizes, int n_in,
                              void* d_out, int out_size, void* d_ws,
                              size_t ws_size, hipStream_t stream) {
  (void)in_sizes;
  (void)n_in;
  (void)out_size;
  const float* inputs = (const float*)d_in[0];
  const float* times = (const float*)d_in[1];
  const int* non_zero = (const int*)d_in[2];
  const float* Wih = (const float*)d_in[3];
  const float* Whh = (const float*)d_in[4];
  const float* bih = (const float*)d_in[5];
  const float* bhh = (const float*)d_in[6];
  const float* dW1 = (const float*)d_in[7];
  const float* db1 = (const float*)d_in[8];
  const float* dW2 = (const float*)d_in[9];
  const float* db2 = (const float*)d_in[10];
  const float* gW1 = (const float*)d_in[11];
  const float* gb1 = (const float*)d_in[12];
  const float* gW2 = (const float*)d_in[13];
  const float* gb2 = (const float*)d_in[14];
  float* out = (float*)d_out;

  char* ws = (char*)d_ws;
  float* wsTd = (float*)ws;                // [0, 512)
  float* wsC = (float*)(ws + 512);         // [512, 1024)   (fallback only)
  float* wsE = (float*)(ws + 1024);        // [1024, 1536)  (fallback only)
  f16* wsA = (f16*)(ws + 1536);            // [1536, +16384)   (fallback only)
  f16* wsB = (f16*)(ws + 1536 + 16384);    // [17920, +16384)  (fallback only)
  int* wsPerm = (int*)(ws + 34816);        // [34816, +2048)
  f16* wsGi = (f16*)(ws + 36864);          // [36864, +66.6MB)
  const size_t GI_BYTES = (size_t)B_LEN * NSTEP * 128 * 4 * sizeof(f16);
  const size_t NEED = 36864 + GI_BYTES;

  hipLaunchKernelGGL(td_kernel, dim3(NSTEP), dim3(256), 0, stream, times,
                     non_zero, wsTd);
  if (ws_size >= NEED) {
    hipLaunchKernelGGL(rank_kernel, dim3(1), dim3(512), 0, stream, non_zero,
                       wsPerm);
    hipLaunchKernelGGL(sde_scan7, dim3(B_LEN), dim3(512), 0, stream, non_zero,
                       inputs, Wih, bih, Whh, bhh, dW1, db1, dW2, db2, gW1, gb1,
                       gW2, gb2, wsTd, wsGi, wsPerm, out);
  } else {
    hipLaunchKernelGGL(ab_kernel, dim3(128), dim3(128), 0, stream, dW1, gW1,
                       dW2, gW2, db2, gb2, wsC, wsE, wsA, wsB);
    hipLaunchKernelGGL(sde_fused_kernel, dim3(B_LEN / 2), dim3(512), 0, stream,
                       inputs, non_zero, Wih, Whh, bih, bhh, dW1, db1, dW2, db2,
                       gW1, gb1, gW2, gb2, wsTd, wsC, wsE, wsA, wsB, out);
  }
}